// Round 18
// baseline (39.984 us; speedup 1.0000x reference)
//
#include <hip/hip_runtime.h>
#include <hip/hip_bf16.h>

typedef __attribute__((ext_vector_type(8))) short bfrag;   // 8 bf16
typedef __attribute__((ext_vector_type(4))) float f32x4;

typedef __attribute__((address_space(1))) const void GV;
typedef __attribute__((address_space(3))) void LV;

static __device__ __forceinline__ float b2f(short s) {
    unsigned u = ((unsigned)(unsigned short)s) << 16;
    float f;
    __builtin_memcpy(&f, &u, 4);
    return f;
}

// ============ fused prep: norms+xb | wt | pe2b(bf16) — all vector ============
__global__ void k_prep(const float* __restrict__ x,
                       const float* __restrict__ w,
                       const float* __restrict__ tcb,
                       float* __restrict__ norms,
                       __hip_bfloat16* __restrict__ xb,
                       __hip_bfloat16* __restrict__ wt,
                       __hip_bfloat16* __restrict__ pe2b) {
    int blk = blockIdx.x;
    if (blk < 2048) {
        int i = blk * 256 + threadIdx.x;            // 524288 quads
        f32x4 v = *(const f32x4*)&x[i * 4];
        __hip_bfloat16 h[4];
        h[0] = __float2bfloat16(v.x);
        h[1] = __float2bfloat16(v.y);
        h[2] = __float2bfloat16(v.z);
        h[3] = __float2bfloat16(v.w);
        *(short4*)&xb[i * 4] = *(const short4*)h;
        float a = fabsf(v.x) + fabsf(v.y) + fabsf(v.z) + fabsf(v.w);
        a += __shfl_xor(a, 1);
        a += __shfl_xor(a, 2);
        a += __shfl_xor(a, 4);
        a += __shfl_xor(a, 8);                      // 16-lane row reduce
        if ((threadIdx.x & 15) == 0) norms[i >> 4] = a;
    } else if (blk < 2432) {
        int i = (blk - 2048) * 256 + threadIdx.x;   // 98304
        int d = i / 192, kk = i - d * 192;
        int c = kk & 63, k = kk >> 6;
        wt[i] = __float2bfloat16(w[d * 192 + c * 3 + k]);
    } else {
        int j = (blk - 2432) * 256 + threadIdx.x;   // 262144 d-quads
        int s = j >> 7, q = j & 127;
        f32x4 tb = *(const f32x4*)&tcb[q * 4];
        float dv0 = expf((float)(4 * q)     * (-9.210340371976184f / 512.0f));
        float dv1 = expf((float)(4 * q + 2) * (-9.210340371976184f / 512.0f));
        float s0v, c0v, s1v, c1v;
        sincosf((float)s * dv0, &s0v, &c0v);
        sincosf((float)s * dv1, &s1v, &c1v);
        __hip_bfloat16 h[4];
        h[0] = __float2bfloat16(s0v + tb.x);
        h[1] = __float2bfloat16(c0v + tb.y);
        h[2] = __float2bfloat16(s1v + tb.z);
        h[3] = __float2bfloat16(c1v + tb.w);
        *(short4*)&pe2b[s * 512 + q * 4] = *(const short4*)h;
    }
}

// ---------- tc[b][t]: wave-per-t, 256-wide aligned float4 windows ----------
__global__ void k_tc(const float* __restrict__ norms, float* __restrict__ tc) {
    int gid = blockIdx.x * 256 + threadIdx.x;
    int wave = gid >> 6;                  // 32768 = (b,t)
    int lane = threadIdx.x & 63;
    int b = wave >> 11, t = wave & 2047;
    const float* nb = norms + (b << 11);
    float thresh = 0.7f * (nb[t] + 1e-8f);
    int res = 0;
    for (int W = (t - 1) >> 8; W >= 0; --W) {
        int sBase = W * 256 + 4 * lane;
        f32x4 v = *(const f32x4*)&nb[sBase];
        int best = -1;
        if (sBase + 0 < t && v.x < thresh) best = sBase + 0;
        if (sBase + 1 < t && v.y < thresh) best = sBase + 1;
        if (sBase + 2 < t && v.z < thresh) best = sBase + 2;
        if (sBase + 3 < t && v.w < thresh) best = sBase + 3;
        unsigned long long m = __ballot(best >= 0);
        if (m) {                                    // highest lane = largest s
            int L = 63 - __clzll(m);
            int smax = __shfl(best, L);
            res = t - smax;
            break;
        }
    }
    if (lane == 0) tc[wave] = (float)res;
}

// == conv-GEMM: 256 blocks x 1024 thr (16 waves/CU), 128d x 128s x 4 batches ==
// Traffic-identical to R15/R17; only wave parallelism doubled (latency hiding).
// Wave = 32d x 32s. All staging -> ONE barrier -> per-batch {MFMA, fold,
// unified store burst}, no barriers/global reads after. LDS 101376 B.
__launch_bounds__(1024, 1)
__global__ void k_gemm(const __hip_bfloat16* __restrict__ xb,
                       const __hip_bfloat16* __restrict__ wt,
                       const __hip_bfloat16* __restrict__ pe2b,
                       const float* __restrict__ tc,
                       const float* __restrict__ tcw,
                       float* __restrict__ out) {
    __shared__ alignas(16) char Smem[101376];
    char* Ps1 = Smem + 66560;                       // 32768 B
    float* Ts = (float*)(Smem + 99328);             // 4 x 128 floats

    const int bid = blockIdx.x;                     // 256 blocks
    const int xcd = bid & 7, v = bid >> 3;          // v in [0,32)
    const int st = (xcd << 1) | (v & 1);            // 16 s-tiles
    const int bbg = (v >> 1) & 3;                   // batch group (4 batches)
    const int d0 = (v >> 3) << 7;                   // {0,128,256,384}
    const int s0 = st << 7;
    const int tid = threadIdx.x;                    // 0..1023
    const int lane = tid & 63;
    const int wv = tid >> 6;                        // 16 waves
    const int wd4 = wv >> 2, ws4 = wv & 3;          // wave = 32d x 32s
    const int lhi = lane >> 4, ll = lane & 15;

    // ---- stage Bs x4: per batch 130 rows x 8 chunks, pre-swizzled src ----
#pragma unroll
    for (int bi = 0; bi < 4; ++bi) {
        const size_t xrow = (size_t)((bbg * 4 + bi) << 11);
        char* Bsb = Smem + bi * 16640;
#pragma unroll
        for (int i = 0; i < 2; ++i) {
            int q = tid + i * 1024;
            if (q < 1040) {
                int row = q >> 3, uu = q & 7;
                int us = uu ^ (row & 7);
                int sg = (s0 - 1 + row) & 2047;
                const __hip_bfloat16* src = xb + (xrow + sg) * 64 + us * 8;
                __builtin_amdgcn_global_load_lds((GV*)src, (LV*)(Bsb + q * 16),
                                                 16, 0, 0);
            }
        }
    }
    // ---- stage Ps (pe2b slice): 2048 chunks, chunk-XOR swizzled src ----
#pragma unroll
    for (int i = 0; i < 2; ++i) {
        int q = tid + i * 1024;
        int sl = q >> 4, c = q & 15;
        int cs = c ^ (sl & 7);
        const __hip_bfloat16* src = pe2b + (size_t)(s0 + sl) * 512 + d0 + cs * 8;
        __builtin_amdgcn_global_load_lds((GV*)src, (LV*)(Ps1 + q * 16), 16, 0, 0);
    }
    // ---- stage Ts: 4 batches x 128 floats = 128 chunks ----
    if (tid < 128) {
        int bi = tid >> 5, o = tid & 31;
        const float* src = tc + ((size_t)((bbg * 4 + bi) << 11)) + s0 + o * 4;
        __builtin_amdgcn_global_load_lds((GV*)src,
                                         (LV*)(Ts + bi * 128 + o * 4), 16, 0, 0);
    }

    // ---- wt fragments (3 taps x 2 kc x 2 m) + tcw, loaded once from L2 ----
    const __hip_bfloat16* wbase =
        wt + (size_t)(d0 + wd4 * 32 + ll) * 192 + lhi * 8;
    bfrag af[3][2][2];                              // [tap][kc][m]
#pragma unroll
    for (int k = 0; k < 3; ++k)
#pragma unroll
        for (int kc = 0; kc < 2; ++kc)
#pragma unroll
            for (int m = 0; m < 2; ++m)
                af[k][kc][m] = *(const bfrag*)(wbase + m * 16 * 192 +
                                               k * 64 + kc * 32);
    f32x4 tw[2];
#pragma unroll
    for (int m = 0; m < 2; ++m)
        tw[m] = *(const f32x4*)&tcw[d0 + wd4 * 32 + m * 16 + lhi * 4];

    __syncthreads();   // ONE barrier: everything staged

    // ==== 4 batch passes: no barriers, no global reads ====
#pragma unroll
    for (int bi = 0; bi < 4; ++bi) {
        const char* Bsb = Smem + bi * 16640;
        f32x4 acc[2][2] = {};
#pragma unroll
        for (int k = 0; k < 3; ++k) {
#pragma unroll
            for (int kc = 0; kc < 2; ++kc) {
                const int colB = kc * 64 + lhi * 16;
                bfrag bf[2];
#pragma unroll
                for (int n = 0; n < 2; ++n) {
                    int rl = ws4 * 32 + n * 16 + ll + k;   // 0..129
                    bf[n] = *(const bfrag*)(Bsb + rl * 128 +
                                            (colB ^ ((rl & 7) << 4)));
                }
#pragma unroll
                for (int m = 0; m < 2; ++m)
#pragma unroll
                    for (int n = 0; n < 2; ++n)
                        acc[m][n] = __builtin_amdgcn_mfma_f32_16x16x32_bf16(
                            af[k][kc][m], bf[n], acc[m][n], 0, 0, 0);
            }
        }

        // fold pe + tc, unified store burst for this batch
        const size_t obase = ((size_t)((bbg * 4 + bi) << 11) + s0) * 512;
#pragma unroll
        for (int n = 0; n < 2; ++n) {
            const int sl = ws4 * 32 + n * 16 + ll;
            const float tcv = Ts[bi * 128 + sl];
            const size_t orow = obase + (size_t)sl * 512;
#pragma unroll
            for (int m = 0; m < 2; ++m) {
                const int dloc = wd4 * 32 + m * 16 + lhi * 4;
                const int pbyte = sl * 256 + ((((dloc >> 3) ^ (sl & 7)) << 4) |
                                              ((dloc << 1) & 15));
                const short4 pv = *(const short4*)(Ps1 + pbyte);
                f32x4 r = acc[m][n];
                r.x += b2f(pv.x) + tcv * tw[m].x;
                r.y += b2f(pv.y) + tcv * tw[m].y;
                r.z += b2f(pv.z) + tcv * tw[m].z;
                r.w += b2f(pv.w) + tcv * tw[m].w;
                *(f32x4*)&out[orow + d0 + dloc] = r;
            }
        }
    }
}

extern "C" void kernel_launch(void* const* d_in, const int* in_sizes, int n_in,
                              void* d_out, int out_size, void* d_ws, size_t ws_size,
                              hipStream_t stream) {
    const float* x   = (const float*)d_in[0];   // (16,2048,64)
    const float* cw  = (const float*)d_in[1];   // (512,64,3)
    const float* tcw = (const float*)d_in[2];   // (512,1)
    const float* tcb = (const float*)d_in[3];   // (512,)
    float* out = (float*)d_out;

    char* ws = (char*)d_ws;
    __hip_bfloat16* xb   = (__hip_bfloat16*)(ws);            // 4,194,304 B
    __hip_bfloat16* wt   = (__hip_bfloat16*)(ws + 4194304);  //   196,608 B
    __hip_bfloat16* pe2b = (__hip_bfloat16*)(ws + 4390912);  // 2,097,152 B
    float* norms         = (float*)(ws + 6488064);           //   131,072 B
    float* tc            = (float*)(ws + 6619136);           //   131,072 B

    hipLaunchKernelGGL(k_prep, dim3(3456), dim3(256), 0, stream,
                       x, cw, tcb, norms, xb, wt, pe2b);
    hipLaunchKernelGGL(k_tc,   dim3(8192), dim3(256), 0, stream, norms, tc);
    hipLaunchKernelGGL(k_gemm, dim3(256),  dim3(1024), 0, stream,
                       xb, wt, pe2b, tc, tcw, out);
}

// Round 19
// 36.197 us; speedup vs baseline: 1.1046x; 1.1046x over previous
//
#include <hip/hip_runtime.h>
#include <hip/hip_bf16.h>

typedef __attribute__((ext_vector_type(8))) short bfrag;   // 8 bf16
typedef __attribute__((ext_vector_type(4))) float f32x4;

typedef __attribute__((address_space(1))) const void GV;
typedef __attribute__((address_space(3))) void LV;

static __device__ __forceinline__ float b2f(short s) {
    unsigned u = ((unsigned)(unsigned short)s) << 16;
    float f;
    __builtin_memcpy(&f, &u, 4);
    return f;
}

// ====== fused prep (32B/thread): norms+xb | wt | pe2b(bf16) ======
// blocks [0,1024): x 2xf32x4 -> xb bf16x8 + L1 norms (8 lanes/row pair)
// blocks [1024,1408): conv_w -> wt[d][k*64+c]
// blocks [1408,1920): pe2b, 8 d-floats per thread
__global__ void k_prep(const float* __restrict__ x,
                       const float* __restrict__ w,
                       const float* __restrict__ tcb,
                       float* __restrict__ norms,
                       __hip_bfloat16* __restrict__ xb,
                       __hip_bfloat16* __restrict__ wt,
                       __hip_bfloat16* __restrict__ pe2b) {
    int blk = blockIdx.x;
    if (blk < 1024) {
        int i = blk * 256 + threadIdx.x;            // 262144 octets
        f32x4 v0 = *(const f32x4*)&x[i * 8];
        f32x4 v1 = *(const f32x4*)&x[i * 8 + 4];
        __hip_bfloat16 h[8];
        h[0] = __float2bfloat16(v0.x); h[1] = __float2bfloat16(v0.y);
        h[2] = __float2bfloat16(v0.z); h[3] = __float2bfloat16(v0.w);
        h[4] = __float2bfloat16(v1.x); h[5] = __float2bfloat16(v1.y);
        h[6] = __float2bfloat16(v1.z); h[7] = __float2bfloat16(v1.w);
        *(short4*)&xb[i * 8]     = *(const short4*)h;
        *(short4*)&xb[i * 8 + 4] = *(const short4*)(h + 4);
        float a = fabsf(v0.x) + fabsf(v0.y) + fabsf(v0.z) + fabsf(v0.w)
                + fabsf(v1.x) + fabsf(v1.y) + fabsf(v1.z) + fabsf(v1.w);
        a += __shfl_xor(a, 1);
        a += __shfl_xor(a, 2);
        a += __shfl_xor(a, 4);                      // 8 lanes = 64 ch
        if ((threadIdx.x & 7) == 0) norms[i >> 3] = a;
    } else if (blk < 1408) {
        int i = (blk - 1024) * 256 + threadIdx.x;   // 98304
        int d = i / 192, kk = i - d * 192;
        int c = kk & 63, k = kk >> 6;
        wt[i] = __float2bfloat16(w[d * 192 + c * 3 + k]);
    } else {
        int j = (blk - 1408) * 256 + threadIdx.x;   // 131072 d-octets
        int s = j >> 6, q = j & 63;                 // d = 8q
        f32x4 tb0 = *(const f32x4*)&tcb[q * 8];
        f32x4 tb1 = *(const f32x4*)&tcb[q * 8 + 4];
        __hip_bfloat16 h[8];
#pragma unroll
        for (int p = 0; p < 4; ++p) {
            float dv = expf((float)(8 * q + 2 * p) * (-9.210340371976184f / 512.0f));
            float sv, cv;
            sincosf((float)s * dv, &sv, &cv);
            float ab = (p < 2) ? ((p == 0) ? tb0.x : tb0.z)
                               : ((p == 2) ? tb1.x : tb1.z);
            float cb = (p < 2) ? ((p == 0) ? tb0.y : tb0.w)
                               : ((p == 2) ? tb1.y : tb1.w);
            h[2 * p]     = __float2bfloat16(sv + ab);
            h[2 * p + 1] = __float2bfloat16(cv + cb);
        }
        *(short4*)&pe2b[s * 512 + q * 8]     = *(const short4*)h;
        *(short4*)&pe2b[s * 512 + q * 8 + 4] = *(const short4*)(h + 4);
    }
}

// ---------- tc[b][t]: wave-per-t, 256-wide aligned float4 windows ----------
__global__ void k_tc(const float* __restrict__ norms, float* __restrict__ tc) {
    int gid = blockIdx.x * 256 + threadIdx.x;
    int wave = gid >> 6;                  // 32768 = (b,t)
    int lane = threadIdx.x & 63;
    int b = wave >> 11, t = wave & 2047;
    const float* nb = norms + (b << 11);
    float thresh = 0.7f * (nb[t] + 1e-8f);
    int res = 0;
    for (int W = (t - 1) >> 8; W >= 0; --W) {
        int sBase = W * 256 + 4 * lane;
        f32x4 v = *(const f32x4*)&nb[sBase];
        int best = -1;
        if (sBase + 0 < t && v.x < thresh) best = sBase + 0;
        if (sBase + 1 < t && v.y < thresh) best = sBase + 1;
        if (sBase + 2 < t && v.z < thresh) best = sBase + 2;
        if (sBase + 3 < t && v.w < thresh) best = sBase + 3;
        unsigned long long m = __ballot(best >= 0);
        if (m) {                                    // highest lane = largest s
            int L = 63 - __clzll(m);
            int smax = __shfl(best, L);
            res = t - smax;
            break;
        }
    }
    if (lane == 0) tc[wave] = (float)res;
}

// == conv-GEMM: 256 blocks x 512 thr (1/CU), 128d x 128s x 4 batches ==
// R15 schedule; epilogue refactored: ALL pe/tc folds into registers first,
// then one back-to-back store burst per batch (max L2 line-merge window).
__launch_bounds__(512, 1)
__global__ void k_gemm(const __hip_bfloat16* __restrict__ xb,
                       const __hip_bfloat16* __restrict__ wt,
                       const __hip_bfloat16* __restrict__ pe2b,
                       const float* __restrict__ tc,
                       const float* __restrict__ tcw,
                       float* __restrict__ out) {
    __shared__ alignas(16) char Smem[101376];
    char* Ps1 = Smem + 66560;                       // 32768 B
    float* Ts = (float*)(Smem + 99328);             // 4 x 128 floats

    const int bid = blockIdx.x;                     // 256 blocks
    const int xcd = bid & 7, v = bid >> 3;          // v in [0,32)
    const int st = (xcd << 1) | (v & 1);            // 16 s-tiles
    const int bbg = (v >> 1) & 3;                   // batch group (4 batches)
    const int d0 = (v >> 3) << 7;                   // {0,128,256,384}
    const int s0 = st << 7;
    const int tid = threadIdx.x;                    // 0..511
    const int lane = tid & 63;
    const int wd = tid >> 6;                        // wave owns 16 d-rows
    const int lhi = lane >> 4, ll = lane & 15;

    // ---- stage Bs x4: per batch 130 rows x 8 chunks, pre-swizzled src ----
#pragma unroll
    for (int bi = 0; bi < 4; ++bi) {
        const size_t xrow = (size_t)((bbg * 4 + bi) << 11);
        char* Bsb = Smem + bi * 16640;
#pragma unroll
        for (int i = 0; i < 3; ++i) {
            int q = tid + i * 512;
            if (q < 1040) {
                int row = q >> 3, uu = q & 7;
                int us = uu ^ (row & 7);
                int sg = (s0 - 1 + row) & 2047;
                const __hip_bfloat16* src = xb + (xrow + sg) * 64 + us * 8;
                __builtin_amdgcn_global_load_lds((GV*)src, (LV*)(Bsb + q * 16),
                                                 16, 0, 0);
            }
        }
    }
    // ---- stage Ps (pe2b slice): 2048 chunks, chunk-XOR swizzled src ----
#pragma unroll
    for (int i = 0; i < 4; ++i) {
        int q = tid + i * 512;
        int sl = q >> 4, c = q & 15;
        int cs = c ^ (sl & 7);
        const __hip_bfloat16* src = pe2b + (size_t)(s0 + sl) * 512 + d0 + cs * 8;
        __builtin_amdgcn_global_load_lds((GV*)src, (LV*)(Ps1 + q * 16), 16, 0, 0);
    }
    // ---- stage Ts: 4 batches x 128 floats = 128 chunks ----
    if (tid < 128) {
        int bi = tid >> 5, o = tid & 31;
        const float* src = tc + ((size_t)((bbg * 4 + bi) << 11)) + s0 + o * 4;
        __builtin_amdgcn_global_load_lds((GV*)src,
                                         (LV*)(Ts + bi * 128 + o * 4), 16, 0, 0);
    }

    // ---- wt fragments (3 taps x 2 kc) + tcw, loaded once from L2 ----
    const __hip_bfloat16* wbase =
        wt + (size_t)(d0 + wd * 16 + ll) * 192 + lhi * 8;
    bfrag af[3][2];                                 // [tap][kc]
#pragma unroll
    for (int k = 0; k < 3; ++k)
#pragma unroll
        for (int kc = 0; kc < 2; ++kc)
            af[k][kc] = *(const bfrag*)(wbase + k * 64 + kc * 32);
    f32x4 tw = *(const f32x4*)&tcw[d0 + wd * 16 + lhi * 4];

    __syncthreads();   // ONE barrier: everything staged

    const int dloc = wd * 16 + lhi * 4;

    // ==== 4 batch passes: no barriers, no global reads ====
#pragma unroll
    for (int bi = 0; bi < 4; ++bi) {
        const char* Bsb = Smem + bi * 16640;
        f32x4 acc[8] = {};
#pragma unroll
        for (int k = 0; k < 3; ++k) {
#pragma unroll
            for (int kc = 0; kc < 2; ++kc) {
                const int colB = kc * 64 + lhi * 16;
                bfrag bf[8];
#pragma unroll
                for (int n = 0; n < 8; ++n) {
                    int rl = n * 16 + ll + k;       // 0..129
                    bf[n] = *(const bfrag*)(Bsb + rl * 128 +
                                            (colB ^ ((rl & 7) << 4)));
                }
#pragma unroll
                for (int n = 0; n < 8; ++n)
                    acc[n] = __builtin_amdgcn_mfma_f32_16x16x32_bf16(
                        af[k][kc], bf[n], acc[n], 0, 0, 0);
            }
        }

        // ---- fold pe + tc into ALL acc first (regs only) ----
#pragma unroll
        for (int n = 0; n < 8; ++n) {
            const int sl = n * 16 + ll;
            const float tcv = Ts[bi * 128 + sl];
            const int pbyte = sl * 256 + ((((dloc >> 3) ^ (sl & 7)) << 4) |
                                          ((dloc << 1) & 15));
            const short4 pv = *(const short4*)(Ps1 + pbyte);
            acc[n].x += b2f(pv.x) + tcv * tw.x;
            acc[n].y += b2f(pv.y) + tcv * tw.y;
            acc[n].z += b2f(pv.z) + tcv * tw.z;
            acc[n].w += b2f(pv.w) + tcv * tw.w;
        }

        // ---- back-to-back store burst (pure stores) ----
        const size_t obase = ((size_t)((bbg * 4 + bi) << 11) + s0) * 512;
#pragma unroll
        for (int n = 0; n < 8; ++n) {
            const int sl = n * 16 + ll;
            *(f32x4*)&out[obase + (size_t)sl * 512 + d0 + dloc] = acc[n];
        }
    }
}

extern "C" void kernel_launch(void* const* d_in, const int* in_sizes, int n_in,
                              void* d_out, int out_size, void* d_ws, size_t ws_size,
                              hipStream_t stream) {
    const float* x   = (const float*)d_in[0];   // (16,2048,64)
    const float* cw  = (const float*)d_in[1];   // (512,64,3)
    const float* tcw = (const float*)d_in[2];   // (512,1)
    const float* tcb = (const float*)d_in[3];   // (512,)
    float* out = (float*)d_out;

    char* ws = (char*)d_ws;
    __hip_bfloat16* xb   = (__hip_bfloat16*)(ws);            // 4,194,304 B
    __hip_bfloat16* wt   = (__hip_bfloat16*)(ws + 4194304);  //   196,608 B
    __hip_bfloat16* pe2b = (__hip_bfloat16*)(ws + 4390912);  // 2,097,152 B
    float* norms         = (float*)(ws + 6488064);           //   131,072 B
    float* tc            = (float*)(ws + 6619136);           //   131,072 B

    hipLaunchKernelGGL(k_prep, dim3(1920), dim3(256), 0, stream,
                       x, cw, tcb, norms, xb, wt, pe2b);
    hipLaunchKernelGGL(k_tc,   dim3(8192), dim3(256), 0, stream, norms, tc);
    hipLaunchKernelGGL(k_gemm, dim3(256),  dim3(512), 0, stream,
                       xb, wt, pe2b, tc, tcw, out);
}